// Round 16
// baseline (27.410 us; speedup 1.0000x reference)
//
#include <hip/hip_runtime.h>

#define NPIX (384*384)        // 147456
#define NSAMP 32
#define ROWS 64               // 32 region rows + 32 affinity rows
#define BINS2 2048            // exponent(8) + 4 mantissa bits; l in [0,1) -> bin <= 2031
#define REPL 2                // LDS histogram replication
#define THREADS 256
#define BLKROW 32             // 64 x 32 = 2048 blocks = exactly 8/CU resident
#define EPB (NPIX / BLKROW)   // 4608 elements per block = 4 full + 1 half iter
#define SELTHREADS 1024

// workspace layout (no zero-init needed anywhere):
//   part [ROWS][BLKROW][BINS2/2] u32  (two u16 counts packed; 8 MB, plain stores)
//   pstat[ROWS][BLKROW]          u64  per-block (n_pos<<32 | f32bits(pos_sum))
// per-block count <= 4608 < 2^16 fits u16.
#define PART_U32   ((size_t)ROWS * BLKROW * (BINS2 / 2))
#define PSTAT_OFF  (PART_U32 * 4)

// Per (row, chunk) block: loss for 4608 pixels -> 2048-bin count histogram in
// LDS (2-way replicated u32), flushed as packed u16-pair u32 stores to a
// private slot. ZERO global atomics (R9 lesson). NEW vs R13: 2-deep load
// pipeline — prefetch it+1's three float4s before processing it. R12-R15's
// VGPR_Count=16 proved the compiler serialized load->use per iteration,
// exposing L2/L3 latency every iteration (R2 evidence: L3-resident replay
// ran same time as HBM-cold -> latency-, not bytes-bound).
__global__ __launch_bounds__(THREADS, 8) void k_hist(
    const float* __restrict__ gt_r, const float* __restrict__ gt_a,
    const float* __restrict__ pr_r, const float* __restrict__ pr_a,
    const float* __restrict__ conf,
    unsigned int* __restrict__ part,
    unsigned long long* __restrict__ pstat,
    float* __restrict__ out)
{
    __shared__ unsigned int s_cnt[BINS2 * REPL];   // 16 KB
    __shared__ unsigned int s_pc;
    __shared__ float s_ps;
    const int tid = threadIdx.x;
    const int row = blockIdx.y;
    const int chunk = blockIdx.x;
    const int samp = row & (NSAMP - 1);
    const float* gt = (row < NSAMP) ? gt_r : gt_a;
    const float* pr = (row < NSAMP) ? pr_r : pr_a;
    const unsigned copy = tid & (REPL - 1);

    // zero d_out for k_sel's atomicAdd (safe: consumed only after this kernel)
    if (row == 0 && chunk == 0 && tid == 0) out[0] = 0.f;

    for (int i = tid; i < BINS2 * REPL; i += THREADS) s_cnt[i] = 0u;
    if (tid == 0) { s_pc = 0u; s_ps = 0.f; }
    __syncthreads();

    const size_t tb = (size_t)samp * NPIX + (size_t)chunk * EPB + (size_t)tid * 4;
    unsigned pc = 0; float ps = 0.f;

#define PROCESS(G, P, C)                                                      \
    {                                                                         \
        float gv[4] = {(G).x, (G).y, (G).z, (G).w};                           \
        float pv[4] = {(P).x, (P).y, (P).z, (P).w};                           \
        float cv[4] = {(C).x, (C).y, (C).z, (C).w};                           \
        _Pragma("unroll")                                                     \
        for (int j = 0; j < 4; ++j) {                                         \
            float d = pv[j] - gv[j];                                          \
            float l = d * d * cv[j];                                          \
            if (gv[j] >= 0.1f) { pc++; ps += l; }                             \
            else {                                                            \
                unsigned bin = __float_as_uint(l) >> 19;                      \
                atomicAdd(&s_cnt[(bin << 1) | copy], 1u);                     \
            }                                                                 \
        }                                                                     \
    }

    // 2-deep pipelined: 4 full iterations + half-width tail (tid < 128)
    float4 g0 = *(const float4*)(gt + tb);
    float4 p0 = *(const float4*)(pr + tb);
    float4 c0 = *(const float4*)(conf + tb);
    #pragma unroll
    for (int it = 0; it < 4; ++it) {
        float4 g1, p1, c1;
        const bool pf = (it < 3) || (tid < 128);
        if (pf) {
            size_t nx = tb + (size_t)(it + 1) * (THREADS * 4);
            g1 = *(const float4*)(gt + nx);
            p1 = *(const float4*)(pr + nx);
            c1 = *(const float4*)(conf + nx);
        }
        PROCESS(g0, p0, c0);
        g0 = g1; p0 = p1; c0 = c1;
    }
    if (tid < 128) PROCESS(g0, p0, c0);
#undef PROCESS

    // wave-reduce positive stats -> LDS (no global atomics)
    for (int off = 32; off; off >>= 1) {
        pc += __shfl_down(pc, off);
        ps += __shfl_down(ps, off);
    }
    if ((tid & 63) == 0) { atomicAdd(&s_pc, pc); atomicAdd(&s_ps, ps); }
    __syncthreads();

    // private flush: pack counts of bins (2i, 2i+1) into one u32, plain stores
    unsigned int* dst = part + ((size_t)row * BLKROW + chunk) * (BINS2 / 2);
    for (int i = tid; i < BINS2 / 2; i += THREADS) {
        unsigned lo = s_cnt[(i << 2) | 0] + s_cnt[(i << 2) | 1];   // cnt(2i)
        unsigned hi = s_cnt[(i << 2) | 2] + s_cnt[(i << 2) | 3];   // cnt(2i+1)
        dst[i] = lo | (hi << 16);
    }

    if (tid == 0)
        pstat[(size_t)row * BLKROW + chunk] =
            ((unsigned long long)s_pc << 32) | (unsigned long long)__float_as_uint(s_ps);
}

// Geometric center of histogram bin b (bins are [lo, lo*(1+1/32)) slices).
__device__ __forceinline__ float bin_center(int b)
{
    return __uint_as_float(((unsigned)b) << 19) * 1.015625f;
}

// Per row, 1024 threads (2 descending ranks/thread): reduce 32 stat pairs,
// sum 32 packed partials (one u32/thread/chunk), two-level inclusive scan,
// boundary bin's partial take approximated by bin_center.
__global__ __launch_bounds__(SELTHREADS) void k_sel(
    const unsigned int* __restrict__ part,
    const unsigned long long* __restrict__ pstat,
    float* __restrict__ out)
{
    const int row = blockIdx.x;           // 0..63
    const int tid = threadIdx.x;          // 0..1023
    __shared__ unsigned s_npos; __shared__ float s_psum;
    __shared__ unsigned wtc[16]; __shared__ float wts[16];

    // wave 0 reduces the 32 per-block stat pairs
    if (tid < 64) {
        unsigned pc = 0; float ps = 0.f;
        if (tid < BLKROW) {
            unsigned long long v = pstat[(size_t)row * BLKROW + tid];
            pc = (unsigned)(v >> 32);
            ps = __uint_as_float((unsigned)(v & 0xFFFFFFFFu));
        }
        for (int off = 32; off; off >>= 1) {
            pc += __shfl_down(pc, off);
            ps += __shfl_down(ps, off);
        }
        if (tid == 0) { s_npos = pc; s_psum = ps; }
    }

    // thread t owns ranks (2t, 2t+1) -> bins (2047-2t, 2046-2t), both inside
    // packed word wi = 1023 - t: hi16 = cnt(2047-2t), lo16 = cnt(2046-2t).
    const unsigned int* base = part + (size_t)row * BLKROW * (BINS2 / 2)
                             + (BINS2 / 2 - 1 - tid);
    unsigned c0 = 0, c1 = 0;
    #pragma unroll
    for (int ch = 0; ch < BLKROW; ++ch) {
        unsigned v = base[(size_t)ch * (BINS2 / 2)];
        c0 += v >> 16;          // rank 2t   (bin 2047-2t)
        c1 += v & 0xFFFFu;      // rank 2t+1 (bin 2046-2t)
    }
    const int bin0 = BINS2 - 1 - 2 * tid;
    const int bin1 = bin0 - 1;
    float s0 = (float)c0 * bin_center(bin0);
    float s1 = (float)c1 * bin_center(bin1);
    unsigned tc = c0 + c1; float ts = s0 + s1;

    // two-level inclusive scan over (tc, ts) in rank order (16 waves)
    unsigned lane = tid & 63, w = tid >> 6;
    unsigned ic = tc; float is = ts;
    #pragma unroll
    for (int off = 1; off < 64; off <<= 1) {
        unsigned uc = __shfl_up(ic, off);
        float    us = __shfl_up(is, off);
        if (lane >= off) { ic += uc; is += us; }
    }
    if (lane == 63) { wtc[w] = ic; wts[w] = is; }
    __syncthreads();
    unsigned woc = 0; float wos = 0.f;
    for (unsigned i = 0; i < w; ++i) { woc += wtc[i]; wos += wts[i]; }
    unsigned before_c = woc + ic - tc;   // count strictly above my first rank
    float    before_s = wos + is - ts;

    const unsigned n_pos = s_npos;
    const float pos_sum = s_psum;
    const unsigned n_neg = NPIX - n_pos;
    const float pos_part = (n_pos > 0u) ? pos_sum / (float)n_pos : 0.f;
    if (n_neg == 0u) {
        if (tid == 0) atomicAdd(out, (pos_part - 1.f) / (float)NSAMP); // sentinel -1
        return;
    }
    unsigned k;
    if (n_pos > 0u) {
        k = 3u * n_pos;
        if (k > n_neg) k = n_neg;
        if (k < 1u) k = 1u;
    } else {
        k = 500u;   // fallback: top-500 (all pixels are negatives when n_pos==0)
    }

    if (before_c < k && before_c + c0 >= k) {
        unsigned kpp = k - before_c;
        float topk = before_s + (float)kpp * bin_center(bin0);
        atomicAdd(out, (pos_part + topk / (float)k) / (float)NSAMP);
    }
    before_c += c0; before_s += s0;
    if (before_c < k && before_c + c1 >= k) {
        unsigned kpp = k - before_c;
        float topk = before_s + (float)kpp * bin_center(bin1);
        atomicAdd(out, (pos_part + topk / (float)k) / (float)NSAMP);
    }
}

extern "C" void kernel_launch(void* const* d_in, const int* in_sizes, int n_in,
                              void* d_out, int out_size, void* d_ws, size_t ws_size,
                              hipStream_t stream)
{
    (void)in_sizes; (void)n_in; (void)out_size; (void)ws_size;
    const float* gt_r = (const float*)d_in[0];
    const float* gt_a = (const float*)d_in[1];
    const float* pr_r = (const float*)d_in[2];
    const float* pr_a = (const float*)d_in[3];
    const float* conf = (const float*)d_in[4];

    char* ws = (char*)d_ws;
    unsigned int*       part  = (unsigned int*)ws;
    unsigned long long* pstat = (unsigned long long*)(ws + PSTAT_OFF);

    dim3 gridH(BLKROW, ROWS);
    k_hist<<<gridH, THREADS, 0, stream>>>(gt_r, gt_a, pr_r, pr_a, conf,
                                          part, pstat, (float*)d_out);
    k_sel<<<ROWS, SELTHREADS, 0, stream>>>(part, pstat, (float*)d_out);
}

// Round 17
// 27.346 us; speedup vs baseline: 1.0024x; 1.0024x over previous
//
#include <hip/hip_runtime.h>

#define NPIX (384*384)        // 147456
#define NSAMP 32
#define ROWS 64               // 32 region rows + 32 affinity rows
#define BINS2 2048            // exponent(8) + 4 mantissa bits; l in [0,1) -> bin <= 2031
#define REPL 2                // LDS histogram replication
#define THREADS 256
#define BLKROW 32             // 64 x 32 = 2048 blocks = exactly 8/CU resident
#define EPB (NPIX / BLKROW)   // 4608 elements per block = 4 full + 1 half iter
#define SELTHREADS 256        // 1 uint4 (8 bins) per thread -> coalesced 1KB wave loads

// workspace layout (no zero-init needed anywhere):
//   part [ROWS][BLKROW][BINS2/2] u32  (two u16 counts packed; 8 MB, plain stores)
//   pstat[ROWS][BLKROW]          u64  per-block (n_pos<<32 | f32bits(pos_sum))
// per-block count <= 4608 < 2^16 fits u16.
#define PART_U32   ((size_t)ROWS * BLKROW * (BINS2 / 2))
#define PSTAT_OFF  (PART_U32 * 4)

// Per (row, chunk) block: loss for 4608 pixels -> 2048-bin count histogram in
// LDS (2-way replicated u32), flushed as packed u16-pair u32 stores to a
// private slot. ZERO global atomics (R9 lesson). R13 structure; NEW: uint4
// LDS init (4 stores vs 16) and uint4 flush reads (ds_read_b128 vs 4x b32)
// to cut fixed per-block LDS op overhead.
__global__ __launch_bounds__(THREADS, 8) void k_hist(
    const float* __restrict__ gt_r, const float* __restrict__ gt_a,
    const float* __restrict__ pr_r, const float* __restrict__ pr_a,
    const float* __restrict__ conf,
    unsigned int* __restrict__ part,
    unsigned long long* __restrict__ pstat,
    float* __restrict__ out)
{
    __shared__ __align__(16) unsigned int s_cnt[BINS2 * REPL];   // 16 KB
    __shared__ unsigned int s_pc;
    __shared__ float s_ps;
    const int tid = threadIdx.x;
    const int row = blockIdx.y;
    const int chunk = blockIdx.x;
    const int samp = row & (NSAMP - 1);
    const float* gt = (row < NSAMP) ? gt_r : gt_a;
    const float* pr = (row < NSAMP) ? pr_r : pr_a;
    const unsigned copy = tid & (REPL - 1);

    // zero d_out for k_sel's atomicAdd (safe: consumed only after this kernel)
    if (row == 0 && chunk == 0 && tid == 0) out[0] = 0.f;

    // uint4 zero-init: 4096 u32 = 1024 uint4 / 256 threads = 4 stores
    {
        uint4* s4 = (uint4*)s_cnt;
        const uint4 z = make_uint4(0u, 0u, 0u, 0u);
        #pragma unroll
        for (int i = 0; i < (BINS2 * REPL) / 4 / THREADS; ++i)
            s4[i * THREADS + tid] = z;
    }
    if (tid == 0) { s_pc = 0u; s_ps = 0.f; }
    __syncthreads();

    const size_t base0 = (size_t)samp * NPIX + (size_t)chunk * EPB;
    unsigned pc = 0; float ps = 0.f;

    #pragma unroll
    for (int it = 0; it < 5; ++it) {            // it==4 is the half-iteration
        if (it == 4 && tid >= 128) break;
        size_t idx = base0 + (size_t)it * THREADS * 4 + (size_t)tid * 4;
        float4 g = *(const float4*)(gt + idx);
        float4 p = *(const float4*)(pr + idx);
        float4 c = *(const float4*)(conf + idx);
        float gv[4] = {g.x, g.y, g.z, g.w};
        float pv[4] = {p.x, p.y, p.z, p.w};
        float cv[4] = {c.x, c.y, c.z, c.w};
        #pragma unroll
        for (int j = 0; j < 4; ++j) {
            float d = pv[j] - gv[j];
            float l = d * d * cv[j];
            if (gv[j] >= 0.1f) { pc++; ps += l; }
            else {
                unsigned bin = __float_as_uint(l) >> 19;   // l < 1 -> bin <= 2031
                atomicAdd(&s_cnt[(bin << 1) | copy], 1u);
            }
        }
    }

    // wave-reduce positive stats -> LDS (no global atomics)
    for (int off = 32; off; off >>= 1) {
        pc += __shfl_down(pc, off);
        ps += __shfl_down(ps, off);
    }
    if ((tid & 63) == 0) { atomicAdd(&s_pc, pc); atomicAdd(&s_ps, ps); }
    __syncthreads();

    // private flush: one uint4 LDS read (both copies of 2 bins) per word
    unsigned int* dst = part + ((size_t)row * BLKROW + chunk) * (BINS2 / 2);
    {
        const uint4* s4 = (const uint4*)s_cnt;
        #pragma unroll
        for (int i = 0; i < (BINS2 / 2) / THREADS; ++i) {
            int w = i * THREADS + tid;
            uint4 v = s4[w];                    // bins 2w (x,y) and 2w+1 (z,w)
            dst[w] = (v.x + v.y) | ((v.z + v.w) << 16);
        }
    }

    if (tid == 0)
        pstat[(size_t)row * BLKROW + chunk] =
            ((unsigned long long)s_pc << 32) | (unsigned long long)__float_as_uint(s_ps);
}

// Geometric center of histogram bin b (bins are [lo, lo*(1+1/32)) slices).
__device__ __forceinline__ float bin_center(int b)
{
    return __uint_as_float(((unsigned)b) << 19) * 1.015625f;
}

// Per row, 256 threads: thread t owns one uint4 (8 bins) per chunk ->
// wave loads are fully coalesced (64 x 16B = 1KB). Reduce 32 stat pairs,
// sum 32 packed partials, two-level inclusive scan in descending-bin order,
// boundary bin's partial take approximated by bin_center.
__global__ __launch_bounds__(SELTHREADS) void k_sel(
    const unsigned int* __restrict__ part,
    const unsigned long long* __restrict__ pstat,
    float* __restrict__ out)
{
    const int row = blockIdx.x;           // 0..63
    const int tid = threadIdx.x;          // 0..255
    __shared__ unsigned s_npos; __shared__ float s_psum;
    __shared__ unsigned wtc[4]; __shared__ float wts[4];

    // wave 0 reduces the 32 per-block stat pairs
    if (tid < 64) {
        unsigned pc = 0; float ps = 0.f;
        if (tid < BLKROW) {
            unsigned long long v = pstat[(size_t)row * BLKROW + tid];
            pc = (unsigned)(v >> 32);
            ps = __uint_as_float((unsigned)(v & 0xFFFFFFFFu));
        }
        for (int off = 32; off; off >>= 1) {
            pc += __shfl_down(pc, off);
            ps += __shfl_down(ps, off);
        }
        if (tid == 0) { s_npos = pc; s_psum = ps; }
    }

    // descending uint4 position: thread t owns uint4 index w4 = 255 - t,
    // i.e. words [4*w4, 4*w4+3] = bins [8*w4, 8*w4+7]. Descending-rank
    // order within the thread: bin 8*w4+7 first.
    const int w4 = (SELTHREADS - 1) - tid;
    const uint4* base = (const uint4*)(part + (size_t)row * BLKROW * (BINS2 / 2)) + w4;
    unsigned cc[8] = {0,0,0,0,0,0,0,0};
    #pragma unroll 8
    for (int ch = 0; ch < BLKROW; ++ch) {
        uint4 v = base[(size_t)ch * ((BINS2 / 2) / 4)];
        cc[0] += v.w >> 16; cc[1] += v.w & 0xFFFFu;   // bins 8w4+7, 8w4+6
        cc[2] += v.z >> 16; cc[3] += v.z & 0xFFFFu;   // bins 8w4+5, 8w4+4
        cc[4] += v.y >> 16; cc[5] += v.y & 0xFFFFu;   // bins 8w4+3, 8w4+2
        cc[6] += v.x >> 16; cc[7] += v.x & 0xFFFFu;   // bins 8w4+1, 8w4
    }
    float ss[8];
    unsigned tc = 0; float ts = 0.f;
    #pragma unroll
    for (int j = 0; j < 8; ++j) {
        ss[j] = (float)cc[j] * bin_center(8 * w4 + 7 - j);
        tc += cc[j]; ts += ss[j];
    }

    // two-level inclusive scan over (tc, ts) in rank order (4 waves)
    unsigned lane = tid & 63, w = tid >> 6;
    unsigned ic = tc; float is = ts;
    #pragma unroll
    for (int off = 1; off < 64; off <<= 1) {
        unsigned uc = __shfl_up(ic, off);
        float    us = __shfl_up(is, off);
        if (lane >= off) { ic += uc; is += us; }
    }
    if (lane == 63) { wtc[w] = ic; wts[w] = is; }
    __syncthreads();
    unsigned woc = 0; float wos = 0.f;
    for (unsigned i = 0; i < w; ++i) { woc += wtc[i]; wos += wts[i]; }
    unsigned before_c = woc + ic - tc;   // count strictly above my first rank
    float    before_s = wos + is - ts;

    const unsigned n_pos = s_npos;
    const float pos_sum = s_psum;
    const unsigned n_neg = NPIX - n_pos;
    const float pos_part = (n_pos > 0u) ? pos_sum / (float)n_pos : 0.f;
    if (n_neg == 0u) {
        if (tid == 0) atomicAdd(out, (pos_part - 1.f) / (float)NSAMP); // sentinel -1
        return;
    }
    unsigned k;
    if (n_pos > 0u) {
        k = 3u * n_pos;
        if (k > n_neg) k = n_neg;
        if (k < 1u) k = 1u;
    } else {
        k = 500u;   // fallback: top-500 (all pixels are negatives when n_pos==0)
    }

    #pragma unroll
    for (int j = 0; j < 8; ++j) {
        if (before_c < k && before_c + cc[j] >= k) {
            unsigned kpp = k - before_c;             // 1 <= kpp <= cc[j]
            float topk = before_s + (float)kpp * bin_center(8 * w4 + 7 - j);
            atomicAdd(out, (pos_part + topk / (float)k) / (float)NSAMP);
        }
        before_c += cc[j]; before_s += ss[j];
    }
}

extern "C" void kernel_launch(void* const* d_in, const int* in_sizes, int n_in,
                              void* d_out, int out_size, void* d_ws, size_t ws_size,
                              hipStream_t stream)
{
    (void)in_sizes; (void)n_in; (void)out_size; (void)ws_size;
    const float* gt_r = (const float*)d_in[0];
    const float* gt_a = (const float*)d_in[1];
    const float* pr_r = (const float*)d_in[2];
    const float* pr_a = (const float*)d_in[3];
    const float* conf = (const float*)d_in[4];

    char* ws = (char*)d_ws;
    unsigned int*       part  = (unsigned int*)ws;
    unsigned long long* pstat = (unsigned long long*)(ws + PSTAT_OFF);

    dim3 gridH(BLKROW, ROWS);
    k_hist<<<gridH, THREADS, 0, stream>>>(gt_r, gt_a, pr_r, pr_a, conf,
                                          part, pstat, (float*)d_out);
    k_sel<<<ROWS, SELTHREADS, 0, stream>>>(part, pstat, (float*)d_out);
}

// Round 18
// 25.771 us; speedup vs baseline: 1.0636x; 1.0611x over previous
//
#include <hip/hip_runtime.h>

#define NPIX (384*384)        // 147456
#define NSAMP 32
#define ROWS 64               // 32 region rows + 32 affinity rows
#define BINS2 2048            // exponent(8) + 4 mantissa bits; l in [0,1) -> bin <= 2031
#define REPL 2                // LDS histogram replication
#define THREADS 256
#define BLKROW 32             // 64 x 32 = 2048 blocks = exactly 8/CU resident
#define EPB (NPIX / BLKROW)   // 4608 elements per block = 4 full + 1 half iter
#define SELTHREADS 1024

// workspace layout (no zero-init needed anywhere):
//   part [ROWS][BLKROW][BINS2/2] u32  (two u16 counts packed; 8 MB, plain stores)
//   pstat[ROWS][BLKROW]          u64  per-block (n_pos<<32 | f32bits(pos_sum))
// per-block count <= 4608 < 2^16 fits u16.
#define PART_U32   ((size_t)ROWS * BLKROW * (BINS2 / 2))
#define PSTAT_OFF  (PART_U32 * 4)

// Per (row, chunk) block: loss for 4608 pixels -> 2048-bin count histogram in
// LDS (2-way replicated u32 — u32 RMW touches 1 bank vs u64's 2), flushed as
// packed u16-pair u32 stores to a private slot. ZERO global atomics
// (R9 lesson: contended device-scope atomics cost ~17us, invisible in SQ).
__global__ __launch_bounds__(THREADS, 8) void k_hist(
    const float* __restrict__ gt_r, const float* __restrict__ gt_a,
    const float* __restrict__ pr_r, const float* __restrict__ pr_a,
    const float* __restrict__ conf,
    unsigned int* __restrict__ part,
    unsigned long long* __restrict__ pstat,
    float* __restrict__ out)
{
    __shared__ unsigned int s_cnt[BINS2 * REPL];   // 16 KB
    __shared__ unsigned int s_pc;
    __shared__ float s_ps;
    const int tid = threadIdx.x;
    const int row = blockIdx.y;
    const int chunk = blockIdx.x;
    const int samp = row & (NSAMP - 1);
    const float* gt = (row < NSAMP) ? gt_r : gt_a;
    const float* pr = (row < NSAMP) ? pr_r : pr_a;
    const unsigned copy = tid & (REPL - 1);

    // zero d_out for k_sel's atomicAdd (safe: consumed only after this kernel)
    if (row == 0 && chunk == 0 && tid == 0) out[0] = 0.f;

    for (int i = tid; i < BINS2 * REPL; i += THREADS) s_cnt[i] = 0u;
    if (tid == 0) { s_pc = 0u; s_ps = 0.f; }
    __syncthreads();

    const size_t base0 = (size_t)samp * NPIX + (size_t)chunk * EPB;
    unsigned pc = 0; float ps = 0.f;

    #pragma unroll
    for (int it = 0; it < 5; ++it) {            // it==4 is the half-iteration
        if (it == 4 && tid >= 128) break;
        size_t idx = base0 + (size_t)it * THREADS * 4 + (size_t)tid * 4;
        float4 g = *(const float4*)(gt + idx);
        float4 p = *(const float4*)(pr + idx);
        float4 c = *(const float4*)(conf + idx);
        float gv[4] = {g.x, g.y, g.z, g.w};
        float pv[4] = {p.x, p.y, p.z, p.w};
        float cv[4] = {c.x, c.y, c.z, c.w};
        #pragma unroll
        for (int j = 0; j < 4; ++j) {
            float d = pv[j] - gv[j];
            float l = d * d * cv[j];
            if (gv[j] >= 0.1f) { pc++; ps += l; }
            else {
                unsigned bin = __float_as_uint(l) >> 19;   // l < 1 -> bin <= 2031
                if (bin > BINS2 - 1) bin = BINS2 - 1;      // safety clamp
                atomicAdd(&s_cnt[(bin << 1) | copy], 1u);
            }
        }
    }

    // wave-reduce positive stats -> LDS (no global atomics)
    for (int off = 32; off; off >>= 1) {
        pc += __shfl_down(pc, off);
        ps += __shfl_down(ps, off);
    }
    if ((tid & 63) == 0) { atomicAdd(&s_pc, pc); atomicAdd(&s_ps, ps); }
    __syncthreads();

    // private flush: pack counts of bins (2i, 2i+1) into one u32, plain stores
    unsigned int* dst = part + ((size_t)row * BLKROW + chunk) * (BINS2 / 2);
    for (int i = tid; i < BINS2 / 2; i += THREADS) {
        unsigned lo = s_cnt[(i << 2) | 0] + s_cnt[(i << 2) | 1];   // cnt(2i)
        unsigned hi = s_cnt[(i << 2) | 2] + s_cnt[(i << 2) | 3];   // cnt(2i+1)
        dst[i] = lo | (hi << 16);
    }

    if (tid == 0)
        pstat[(size_t)row * BLKROW + chunk] =
            ((unsigned long long)s_pc << 32) | (unsigned long long)__float_as_uint(s_ps);
}

// Geometric center of histogram bin b (bins are [lo, lo*(1+1/32)) slices).
__device__ __forceinline__ float bin_center(int b)
{
    return __uint_as_float(((unsigned)b) << 19) * 1.015625f;
}

// Per row, 1024 threads (2 descending ranks/thread): reduce 32 stat pairs,
// sum 32 packed partials (one u32/thread/chunk), two-level inclusive scan,
// boundary bin's partial take approximated by bin_center.
__global__ __launch_bounds__(SELTHREADS) void k_sel(
    const unsigned int* __restrict__ part,
    const unsigned long long* __restrict__ pstat,
    float* __restrict__ out)
{
    const int row = blockIdx.x;           // 0..63
    const int tid = threadIdx.x;          // 0..1023
    __shared__ unsigned s_npos; __shared__ float s_psum;
    __shared__ unsigned wtc[16]; __shared__ float wts[16];

    // wave 0 reduces the 32 per-block stat pairs
    if (tid < 64) {
        unsigned pc = 0; float ps = 0.f;
        if (tid < BLKROW) {
            unsigned long long v = pstat[(size_t)row * BLKROW + tid];
            pc = (unsigned)(v >> 32);
            ps = __uint_as_float((unsigned)(v & 0xFFFFFFFFu));
        }
        for (int off = 32; off; off >>= 1) {
            pc += __shfl_down(pc, off);
            ps += __shfl_down(ps, off);
        }
        if (tid == 0) { s_npos = pc; s_psum = ps; }
    }

    // thread t owns ranks (2t, 2t+1) -> bins (2047-2t, 2046-2t), both inside
    // packed word wi = 1023 - t: hi16 = cnt(2047-2t), lo16 = cnt(2046-2t).
    const unsigned int* base = part + (size_t)row * BLKROW * (BINS2 / 2)
                             + (BINS2 / 2 - 1 - tid);
    unsigned c0 = 0, c1 = 0;
    #pragma unroll
    for (int ch = 0; ch < BLKROW; ++ch) {
        unsigned v = base[(size_t)ch * (BINS2 / 2)];
        c0 += v >> 16;          // rank 2t   (bin 2047-2t)
        c1 += v & 0xFFFFu;      // rank 2t+1 (bin 2046-2t)
    }
    const int bin0 = BINS2 - 1 - 2 * tid;
    const int bin1 = bin0 - 1;
    float s0 = (float)c0 * bin_center(bin0);
    float s1 = (float)c1 * bin_center(bin1);
    unsigned tc = c0 + c1; float ts = s0 + s1;

    // two-level inclusive scan over (tc, ts) in rank order (16 waves)
    unsigned lane = tid & 63, w = tid >> 6;
    unsigned ic = tc; float is = ts;
    #pragma unroll
    for (int off = 1; off < 64; off <<= 1) {
        unsigned uc = __shfl_up(ic, off);
        float    us = __shfl_up(is, off);
        if (lane >= off) { ic += uc; is += us; }
    }
    if (lane == 63) { wtc[w] = ic; wts[w] = is; }
    __syncthreads();
    unsigned woc = 0; float wos = 0.f;
    for (unsigned i = 0; i < w; ++i) { woc += wtc[i]; wos += wts[i]; }
    unsigned before_c = woc + ic - tc;   // count strictly above my first rank
    float    before_s = wos + is - ts;

    const unsigned n_pos = s_npos;
    const float pos_sum = s_psum;
    const unsigned n_neg = NPIX - n_pos;
    const float pos_part = (n_pos > 0u) ? pos_sum / (float)n_pos : 0.f;
    if (n_neg == 0u) {
        if (tid == 0) atomicAdd(out, (pos_part - 1.f) / (float)NSAMP); // sentinel -1
        return;
    }
    unsigned k;
    if (n_pos > 0u) {
        k = 3u * n_pos;
        if (k > n_neg) k = n_neg;
        if (k < 1u) k = 1u;
    } else {
        k = 500u;   // fallback: top-500 (all pixels are negatives when n_pos==0)
    }

    if (before_c < k && before_c + c0 >= k) {
        unsigned kpp = k - before_c;
        float topk = before_s + (float)kpp * bin_center(bin0);
        atomicAdd(out, (pos_part + topk / (float)k) / (float)NSAMP);
    }
    before_c += c0; before_s += s0;
    if (before_c < k && before_c + c1 >= k) {
        unsigned kpp = k - before_c;
        float topk = before_s + (float)kpp * bin_center(bin1);
        atomicAdd(out, (pos_part + topk / (float)k) / (float)NSAMP);
    }
}

extern "C" void kernel_launch(void* const* d_in, const int* in_sizes, int n_in,
                              void* d_out, int out_size, void* d_ws, size_t ws_size,
                              hipStream_t stream)
{
    (void)in_sizes; (void)n_in; (void)out_size; (void)ws_size;
    const float* gt_r = (const float*)d_in[0];
    const float* gt_a = (const float*)d_in[1];
    const float* pr_r = (const float*)d_in[2];
    const float* pr_a = (const float*)d_in[3];
    const float* conf = (const float*)d_in[4];

    char* ws = (char*)d_ws;
    unsigned int*       part  = (unsigned int*)ws;
    unsigned long long* pstat = (unsigned long long*)(ws + PSTAT_OFF);

    dim3 gridH(BLKROW, ROWS);
    k_hist<<<gridH, THREADS, 0, stream>>>(gt_r, gt_a, pr_r, pr_a, conf,
                                          part, pstat, (float*)d_out);
    k_sel<<<ROWS, SELTHREADS, 0, stream>>>(part, pstat, (float*)d_out);
}